// Round 6
// baseline (614.783 us; speedup 1.0000x reference)
//
#include <hip/hip_runtime.h>
#include <math.h>

#define BATCH 512
#define DIM 256
#define HEADS 4
#define KD 16
#define VD 64
#define NQ 196
#define CHW (DIM * NQ)   // 50176

typedef __attribute__((ext_vector_type(8))) short short8;
typedef __attribute__((ext_vector_type(4))) float f32x4;

#define MFMA16(A, B, C) __builtin_amdgcn_mfma_f32_16x16x32_bf16((A), (B), (C), 0, 0, 0)

__device__ __forceinline__ unsigned short f2bf(float f) {
    unsigned int u = __float_as_uint(f);
    u += 0x7FFFu + ((u >> 16) & 1u);          // round-to-nearest-even
    return (unsigned short)(u >> 16);
}
__device__ __forceinline__ float bf2f(unsigned short h) {
    return __uint_as_float(((unsigned int)h) << 16);
}

// ---------------- LDS layout (bytes) ----------------
// featU bf16 [208][72] = 29952 overlays QC (16640) + P0[0..13311]
#define OFF_QC    0          // bf16 [208][40] = 16640  (packed [qh|ql])
#define OFF_P0    16640      // bf16 [208][40] = 16640  (P ping)
#define OFF_P1    33280      // bf16 [208][40] = 16640  (P pong)
#define OFF_QRAW  49920      // fp32 [16][208] = 13312
#define OFF_KB1   63232      // bf16 [224][40] = 17920  ([kh|kh]); proj yr overlay
#define OFF_KB2   81152      // bf16 [224][40] = 17920  ([kl|0])
#define OFF_VBH   99072      // bf16 [64][232] = 29696
#define OFF_VBL   128768     // bf16 [64][232] = 29696
#define OFF_DEN4  158464     // fp32 [208][4]  = 3328
#define OFF_SB    161792     // fp32 [96]
#define OFF_TB    162176     // fp32 [96]
#define OFF_DWS   162560     // fp32 [16]
#define OFF_DWT   162624     // fp32 [16]
#define SMEM_BYTES 162688    // <= 163840

// -------------------- kernel 0: bias expand + weight hi/lo precompute ------------
__global__ __launch_bounds__(256)
void prep_kernel(const float* __restrict__ attn_biases,
                 const int* __restrict__ bias_idxs,
                 const float* __restrict__ qkv_w,
                 const float* __restrict__ proj_w,
                 float* __restrict__ biasg,
                 unsigned short* __restrict__ whH,
                 unsigned short* __restrict__ whL,
                 unsigned short* __restrict__ pwH,
                 unsigned short* __restrict__ pwL) {
    int i = blockIdx.x * 256 + threadIdx.x;
    const int T1 = HEADS * NQ * NQ;        // 153664
    const int T2 = HEADS * 96 * 64;        // 24576
    const int T3 = DIM * DIM;              // 65536
    if (i < T1) {
        int h = i / (NQ * NQ);
        int r = i - h * (NQ * NQ);
        biasg[i] = attn_biases[h * NQ + bias_idxs[r]];
    } else if (i < T1 + T2) {
        int j = i - T1;
        float v = qkv_w[j];
        unsigned short hh = f2bf(v);
        whH[j] = hh;
        whL[j] = f2bf(v - bf2f(hh));
    } else if (i < T1 + T2 + T3) {
        int j = i - T1 - T2;
        float v = proj_w[j];
        unsigned short hh = f2bf(v);
        pwH[j] = hh;
        pwL[j] = f2bf(v - bf2f(hh));
    }
}

// ------------- kernel 1: fused cascaded attention + projection, MFMA -------------
// Projection is accumulated PER HEAD in persistent registers (prj[13], 52 VGPR):
// after each head's PV epilogue, relu'd y_h (bf16) sits in the dead K-buffer LDS
// region and is consumed by 52 MFMAs/wave. No yrelu global round-trip at all.
__global__ __launch_bounds__(1024, 4)
void cascade_attn_kernel(const float* __restrict__ x,
                         const unsigned short* __restrict__ whH,
                         const unsigned short* __restrict__ whL,
                         const float* __restrict__ qkv_g,
                         const float* __restrict__ qkv_b,
                         const float* __restrict__ qkv_rm,
                         const float* __restrict__ qkv_rv,
                         const float* __restrict__ dw_w,
                         const float* __restrict__ dw_g,
                         const float* __restrict__ dw_b,
                         const float* __restrict__ dw_rm,
                         const float* __restrict__ dw_rv,
                         const float* __restrict__ biasg,
                         const unsigned short* __restrict__ pwH,
                         const unsigned short* __restrict__ pwL,
                         const float* __restrict__ pg,
                         const float* __restrict__ pb,
                         const float* __restrict__ prm,
                         const float* __restrict__ prv,
                         float* __restrict__ out) {
    extern __shared__ __align__(16) char smem[];
    unsigned short* featU = (unsigned short*)(smem + OFF_QC);   // [208][72] overlay
    unsigned short* qc    = (unsigned short*)(smem + OFF_QC);   // [208][40] [qh|ql]
    unsigned short* Pb0   = (unsigned short*)(smem + OFF_P0);
    unsigned short* Pb1   = (unsigned short*)(smem + OFF_P1);
    float*          qraw  = (float*)(smem + OFF_QRAW);          // [16][208]
    unsigned short* kb1   = (unsigned short*)(smem + OFF_KB1);  // [224][40] [kh|kh]
    unsigned short* kb2   = (unsigned short*)(smem + OFF_KB2);  // [224][40] [kl|0]
    unsigned short* vbH   = (unsigned short*)(smem + OFF_VBH);  // [64][232]
    unsigned short* vbL   = (unsigned short*)(smem + OFF_VBL);
    float*          den4  = (float*)(smem + OFF_DEN4);          // [208][4]
    float*          sbT   = (float*)(smem + OFF_SB);
    float*          tbT   = (float*)(smem + OFF_TB);
    float*          dwsT  = (float*)(smem + OFF_DWS);
    float*          dwtT  = (float*)(smem + OFF_DWT);
    // relu'd y_h for proj-accum: [208][72] bf16 = 29952 B, lives in dead kb1+kb2
    unsigned short* yrL   = (unsigned short*)(smem + OFF_KB1);

    const int b    = blockIdx.x;
    const int tid  = threadIdx.x;
    const int w    = tid >> 6;
    const int li   = tid & 15;
    const int quad = (tid >> 4) & 3;
    const int tn0  = tid % NQ;     // walk seeds
    const int tc0  = tid / NQ;

    // persistent projection accumulators: wave w owns o-tile [w*16, w*16+16)
    f32x4 prj[13];
    #pragma unroll
    for (int nt = 0; nt < 13; ++nt) prj[nt] = (f32x4){0.f, 0.f, 0.f, 0.f};

    // ---- init: zero ALL of LDS (pads must be exactly 0 for MFMA k-padding) ----
    for (int t = tid; t < SMEM_BYTES / 4; t += 1024) ((unsigned int*)smem)[t] = 0u;
    __syncthreads();
    // feat = bf16(x chunk 0), layout [n][72c]
    for (int t = tid; t < VD * NQ; t += 1024) {
        int n = t % NQ, c = t / NQ;
        featU[n * 72 + c] = f2bf(x[((size_t)b * DIM + c) * NQ + n]);
    }
    __syncthreads();

    for (int h = 0; h < HEADS; ++h) {
        // ---- prologue: fold BN into (s,t) tables ----
        if (tid < 96) {
            float s = qkv_g[h * 96 + tid] * rsqrtf(qkv_rv[h * 96 + tid] + 1e-5f);
            sbT[tid] = s;
            tbT[tid] = qkv_b[h * 96 + tid] - qkv_rm[h * 96 + tid] * s;
        } else if (tid < 112) {
            int c = tid - 96;
            float s = dw_g[h * 16 + c] * rsqrtf(dw_rv[h * 16 + c] + 1e-5f);
            dwsT[c] = s;
            dwtT[c] = dw_b[h * 16 + c] - dw_rm[h * 16 + c] * s;
        }
        __syncthreads();

        // ---- phase B: QKV = W(hi+lo) x feat(bf16); W hi/lo PRECOMPUTED ----
        for (int T = w; T < 78; T += 16) {
            int ot = T / 13, nt = T - ot * 13;
            const size_t wb = ((size_t)h * 96 + ot * 16 + li) * 64;
            short8 ah0 = *(const short8*)(whH + wb + quad * 8);
            short8 al0 = *(const short8*)(whL + wb + quad * 8);
            short8 ah1 = *(const short8*)(whH + wb + 32 + quad * 8);
            short8 al1 = *(const short8*)(whL + wb + 32 + quad * 8);
            short8 b0 = *(const short8*)(featU + (nt * 16 + li) * 72 + quad * 8);
            short8 b1 = *(const short8*)(featU + (nt * 16 + li) * 72 + 32 + quad * 8);
            f32x4 acc = {0.f, 0.f, 0.f, 0.f};
            acc = MFMA16(ah0, b0, acc);
            acc = MFMA16(al0, b0, acc);
            acc = MFMA16(ah1, b1, acc);
            acc = MFMA16(al1, b1, acc);
            int n = nt * 16 + li;
            bool nok = (n < NQ);
            #pragma unroll
            for (int r = 0; r < 4; ++r) {
                int o = ot * 16 + quad * 4 + r;
                float val = acc[r] * sbT[o] + tbT[o];
                if (nok) {
                    if (o < 16) {
                        qraw[o * 208 + n] = val;
                    } else if (o < 32) {
                        int c = o - 16;
                        unsigned short hh = f2bf(val);
                        kb1[n * 40 + c] = hh;
                        kb1[n * 40 + 16 + c] = hh;              // duplicate kh into upper K-half
                        kb2[n * 40 + c] = f2bf(val - bf2f(hh)); // kl (upper half stays 0)
                    } else {
                        int d = o - 32;
                        unsigned short hh = f2bf(val);
                        vbH[d * 232 + n] = hh;
                        vbL[d * 232 + n] = f2bf(val - bf2f(hh));
                    }
                }
            }
        }
        __syncthreads();

        // ---- phase C: depthwise 5x5 conv + BN + *0.25 -> qc = [qh|ql] ----
        {
            int n = tn0, c = tc0, py = tn0 / 14, px = tn0 - (tn0 / 14) * 14;
            for (int t = tid; t < KD * NQ; t += 1024) {
                const float* qr = qraw + c * 208;
                const float* wdc = dw_w + ((size_t)h * KD + c) * 25;
                float accv = 0.f;
                #pragma unroll
                for (int ky = 0; ky < 5; ++ky) {
                    int yy = py + ky - 2;
                    if (yy < 0 || yy >= 14) continue;
                    #pragma unroll
                    for (int kx = 0; kx < 5; ++kx) {
                        int xx = px + kx - 2;
                        if (xx < 0 || xx >= 14) continue;
                        accv = fmaf(wdc[ky * 5 + kx], qr[yy * 14 + xx], accv);
                    }
                }
                float val = fmaf(accv, dwsT[c], dwtT[c]) * 0.25f;
                unsigned short hh = f2bf(val);
                qc[n * 40 + c] = hh;
                qc[n * 40 + 16 + c] = f2bf(val - bf2f(hh));
                n += 44; c += 5; px += 2; py += 3;
                if (px >= 14) { px -= 14; ++py; }
                if (n >= NQ) { n -= NQ; ++c; py -= 14; }
            }
        }
        if (tid < 832) den4[tid] = 0.f;
        __syncthreads();

        // ---- phase D: attention, Pb ping-pong: S(mi+1) || den(mi) || PV(mi) ----
        f32x4 pacc[4];
        #pragma unroll
        for (int s = 0; s < 4; ++s) pacc[s] = (f32x4){0.f, 0.f, 0.f, 0.f};

        auto spass = [&](int mi2, unsigned short* __restrict__ PbW) {
            for (int T = w; T < 26; T += 16) {
                int s = (T >= 13) ? 1 : 0;
                int nt = T - s * 13;
                int n0 = nt * 16;
                int mg = mi2 * 32 + s * 16 + li;       // global key index
                bool mok = (mg < NQ);
                // coalesced bias loads: for fixed (quad,r), li -> consecutive m
                float bias4[4];
                #pragma unroll
                for (int r = 0; r < 4; ++r) {
                    int n = n0 + quad * 4 + r;
                    int ni = n < NQ ? n : NQ - 1;
                    int mgi = mg < NQ ? mg : NQ - 1;
                    bias4[r] = biasg[(size_t)h * (NQ * NQ) + ni * NQ + mgi];
                }
                short8 q  = *(const short8*)(qc  + (n0 + li) * 40 + quad * 8);
                short8 k1 = *(const short8*)(kb1 + mg * 40 + quad * 8);
                short8 k2 = *(const short8*)(kb2 + mg * 40 + quad * 8);
                f32x4 acc = {0.f, 0.f, 0.f, 0.f};
                acc = MFMA16(q, k1, acc);   // qh*kh + ql*kh
                acc = MFMA16(q, k2, acc);   // qh*kl
                #pragma unroll
                for (int r = 0; r < 4; ++r) {
                    float e = mok ? __expf(acc[r] + bias4[r]) : 0.f;
                    PbW[(n0 + quad * 4 + r) * 40 + s * 16 + li] = f2bf(e);
                }
            }
        };

        spass(0, Pb0);
        __syncthreads();

        for (int mi = 0; mi < 7; ++mi) {
            unsigned short* PbR = (mi & 1) ? Pb1 : Pb0;
            unsigned short* PbW = (mi & 1) ? Pb0 : Pb1;
            if (mi < 6) spass(mi + 1, PbW);

            // den-pass: row sums of the bf16 P actually fed to MFMA
            if (tid < 832) {
                int n = tid >> 2, part = tid & 3;
                short8 pv = *(const short8*)(PbR + n * 40 + part * 8);
                float sum = 0.f;
                #pragma unroll
                for (int j = 0; j < 8; ++j) sum += bf2f((unsigned short)pv[j]);
                den4[n * 4 + part] += sum;
            }
            // PV: out += P x V(hi+lo); STATIC slot indexing (rule #20)
            #pragma unroll
            for (int slot = 0; slot < 4; ++slot) {
                int T = w + slot * 16;
                if (T < 52) {
                    int dt = T / 13, nt = T - dt * 13;
                    short8 p  = *(const short8*)(PbR + (nt * 16 + li) * 40 + quad * 8);
                    short8 vh = *(const short8*)(vbH + (dt * 16 + li) * 232 + mi * 32 + quad * 8);
                    short8 vl = *(const short8*)(vbL + (dt * 16 + li) * 232 + mi * 32 + quad * 8);
                    pacc[slot] = MFMA16(p, vh, pacc[slot]);
                    pacc[slot] = MFMA16(p, vl, pacc[slot]);
                }
            }
            __syncthreads();
        }

        // ---- PV epilogue: normalize, write new feat (pre-relu) AND relu'd yrL ----
        // yrL sits in kb1/kb2 (dead after last spass). Rows 196..207 hold stale
        // finite K data: MFMA garbage in B-row n only affects output col n >= NQ,
        // which is never stored.
        #pragma unroll
        for (int slot = 0; slot < 4; ++slot) {
            int T = w + slot * 16;
            if (T < 52) {
                int dt = T / 13, nt = T - dt * 13;
                int d = dt * 16 + li;
                #pragma unroll
                for (int r = 0; r < 4; ++r) {
                    int n = nt * 16 + quad * 4 + r;
                    if (n < NQ) {
                        f32x4 dv = *(const f32x4*)(den4 + n * 4);
                        float dn = (dv.x + dv.y) + (dv.z + dv.w);
                        float val = pacc[slot][r] / dn;
                        unsigned short u = f2bf(val);
                        featU[n * 72 + d] = u;
                        yrL[n * 72 + d] = (u & 0x8000u) ? (unsigned short)0 : u;
                    }
                }
            }
        }
        __syncthreads();

        // ---- proj-accum: prj += pw[:, h*64:(h+1)*64] x relu(y_h)  (52 MFMA/wave)
        // Same k-chunk order (ascending, hi before lo) as the old 8-step loop ->
        // bit-identical summation.
        {
            const int o0 = w * 16;
            #pragma unroll
            for (int ks2 = 0; ks2 < 2; ++ks2) {
                const size_t wb2 = (size_t)(o0 + li) * 256 + h * 64 + ks2 * 32 + quad * 8;
                short8 ah = *(const short8*)(pwH + wb2);
                short8 al = *(const short8*)(pwL + wb2);
                #pragma unroll
                for (int nt = 0; nt < 13; ++nt) {
                    short8 bx = *(const short8*)(yrL + (nt * 16 + li) * 72 + ks2 * 32 + quad * 8);
                    prj[nt] = MFMA16(ah, bx, prj[nt]);
                    prj[nt] = MFMA16(al, bx, prj[nt]);
                }
            }
        }

        // ---- cascade add for next head (direct x reads, coalesced) ----
        if (h < 3) {
            for (int t = tid; t < VD * NQ; t += 1024) {
                int n = t % NQ, c = t / NQ;
                float v = bf2f(featU[n * 72 + c]) + x[((size_t)b * DIM + (h + 1) * VD + c) * NQ + n];
                featU[n * 72 + c] = f2bf(v);
            }
            // re-zero feat pad rows 196..207 (dirtied by Pb/qc overlays)
            for (int t = tid; t < 12 * 64; t += 1024)
                featU[(NQ + t / 64) * 72 + (t & 63)] = 0;
        }
        __syncthreads();
    }

    // ---- final projection epilogue: folded BN + fp32 store ([b][o][n], b fixed)
    {
        const int o0 = w * 16;
        #pragma unroll
        for (int r = 0; r < 4; ++r) {
            int o = o0 + quad * 4 + r;
            float s = pg[o] * rsqrtf(prv[o] + 1e-5f);
            float t = pb[o] - prm[o] * s;
            #pragma unroll
            for (int nt = 0; nt < 13; ++nt) {
                int n = nt * 16 + li;
                if (n < NQ)
                    out[(size_t)b * CHW + (size_t)o * NQ + n] = fmaf(prj[nt][r], s, t);
            }
        }
    }
}

// -------------------- launch --------------------
extern "C" void kernel_launch(void* const* d_in, const int* in_sizes, int n_in,
                              void* d_out, int out_size, void* d_ws, size_t ws_size,
                              hipStream_t stream) {
    const float* x        = (const float*)d_in[0];
    const float* qkv_w    = (const float*)d_in[1];
    const float* qkv_g    = (const float*)d_in[2];
    const float* qkv_b    = (const float*)d_in[3];
    const float* qkv_rm   = (const float*)d_in[4];
    const float* qkv_rv   = (const float*)d_in[5];
    const float* dw_w     = (const float*)d_in[6];
    const float* dw_g     = (const float*)d_in[7];
    const float* dw_b     = (const float*)d_in[8];
    const float* dw_rm    = (const float*)d_in[9];
    const float* dw_rv    = (const float*)d_in[10];
    const float* proj_w   = (const float*)d_in[11];
    const float* proj_g   = (const float*)d_in[12];
    const float* proj_b   = (const float*)d_in[13];
    const float* proj_rm  = (const float*)d_in[14];
    const float* proj_rv  = (const float*)d_in[15];
    const float* attn_bs  = (const float*)d_in[16];
    const int*   bias_idx = (const int*)d_in[17];

    char* ws = (char*)d_ws;
    float* biasg = (float*)ws;                                    // 614656 B
    unsigned short* whH = (unsigned short*)(ws + 614656);         // 49152 B
    unsigned short* whL = (unsigned short*)(ws + 663808);         // 49152 B
    unsigned short* pwH = (unsigned short*)(ws + 712960);         // 131072 B
    unsigned short* pwL = (unsigned short*)(ws + 844032);         // 131072 B (end 975104)

    {
        int total = HEADS * NQ * NQ + HEADS * 96 * 64 + DIM * DIM;  // 243776
        hipLaunchKernelGGL(prep_kernel, dim3((total + 255) / 256), dim3(256),
                           0, stream, attn_bs, bias_idx, qkv_w, proj_w,
                           biasg, whH, whL, pwH, pwL);
    }
    hipLaunchKernelGGL(cascade_attn_kernel, dim3(BATCH), dim3(1024),
                       SMEM_BYTES, stream,
                       x, whH, whL, qkv_g, qkv_b, qkv_rm, qkv_rv,
                       dw_w, dw_g, dw_b, dw_rm, dw_rv, biasg,
                       pwH, pwL, proj_g, proj_b, proj_rm, proj_rv,
                       (float*)d_out);
}

// Round 7
// 527.774 us; speedup vs baseline: 1.1649x; 1.1649x over previous
//
#include <hip/hip_runtime.h>
#include <math.h>

#define BATCH 512
#define DIM 256
#define HEADS 4
#define KD 16
#define VD 64
#define NQ 196
#define CHW (DIM * NQ)   // 50176

typedef __attribute__((ext_vector_type(8))) short short8;
typedef __attribute__((ext_vector_type(4))) float f32x4;

#define MFMA16(A, B, C) __builtin_amdgcn_mfma_f32_16x16x32_bf16((A), (B), (C), 0, 0, 0)

__device__ __forceinline__ unsigned short f2bf(float f) {
    unsigned int u = __float_as_uint(f);
    u += 0x7FFFu + ((u >> 16) & 1u);          // round-to-nearest-even
    return (unsigned short)(u >> 16);
}
__device__ __forceinline__ float bf2f(unsigned short h) {
    return __uint_as_float(((unsigned int)h) << 16);
}

// ---------------- LDS layout (bytes) ----------------
// featU bf16 [208][72] = 29952 overlays QC (16640) + P0[0..13311]
#define OFF_QC    0          // bf16 [208][40] = 16640  (packed [qh|ql])
#define OFF_P0    16640      // bf16 [208][40] = 16640  (P ping)
#define OFF_P1    33280      // bf16 [208][40] = 16640  (P pong)
#define OFF_QRAW  49920      // fp32 [16][208] = 13312
#define OFF_KB1   63232      // bf16 [224][40] = 17920  ([kh|kh])
#define OFF_KB2   81152      // bf16 [224][40] = 17920  ([kl|0])
#define OFF_VBH   99072      // bf16 [64][232] = 29696
#define OFF_VBL   128768     // bf16 [64][232] = 29696
#define OFF_DEN4  158464     // fp32 [208][4]  = 3328
#define OFF_SB    161792     // fp32 [96]
#define OFF_TB    162176     // fp32 [96]
#define OFF_DWS   162560     // fp32 [16]
#define OFF_DWT   162624     // fp32 [16]
#define SMEM_BYTES 162688    // <= 163840
// proj phase: yL bf16 [208][264] = 109824 B overlays offsets 0..109824 (all dead)

// -------------------- kernel 0: bias expand + weight hi/lo precompute ------------
__global__ __launch_bounds__(256)
void prep_kernel(const float* __restrict__ attn_biases,
                 const int* __restrict__ bias_idxs,
                 const float* __restrict__ qkv_w,
                 const float* __restrict__ proj_w,
                 float* __restrict__ biasg,
                 unsigned short* __restrict__ whH,
                 unsigned short* __restrict__ whL,
                 unsigned short* __restrict__ pwH,
                 unsigned short* __restrict__ pwL) {
    int i = blockIdx.x * 256 + threadIdx.x;
    const int T1 = HEADS * NQ * NQ;        // 153664
    const int T2 = HEADS * 96 * 64;        // 24576
    const int T3 = DIM * DIM;              // 65536
    if (i < T1) {
        int h = i / (NQ * NQ);
        int r = i - h * (NQ * NQ);
        biasg[i] = attn_biases[h * NQ + bias_idxs[r]];
    } else if (i < T1 + T2) {
        int j = i - T1;
        float v = qkv_w[j];
        unsigned short hh = f2bf(v);
        whH[j] = hh;
        whL[j] = f2bf(v - bf2f(hh));
    } else if (i < T1 + T2 + T3) {
        int j = i - T1 - T2;
        float v = proj_w[j];
        unsigned short hh = f2bf(v);
        pwH[j] = hh;
        pwL[j] = f2bf(v - bf2f(hh));
    }
}

// ------------- kernel 1: fused cascaded attention + projection, MFMA -------------
__global__ __launch_bounds__(1024, 4)
void cascade_attn_kernel(const float* __restrict__ x,
                         const unsigned short* __restrict__ whH,
                         const unsigned short* __restrict__ whL,
                         const float* __restrict__ qkv_g,
                         const float* __restrict__ qkv_b,
                         const float* __restrict__ qkv_rm,
                         const float* __restrict__ qkv_rv,
                         const float* __restrict__ dw_w,
                         const float* __restrict__ dw_g,
                         const float* __restrict__ dw_b,
                         const float* __restrict__ dw_rm,
                         const float* __restrict__ dw_rv,
                         const float* __restrict__ biasg,
                         unsigned short* __restrict__ yrelu,
                         const unsigned short* __restrict__ pwH,
                         const unsigned short* __restrict__ pwL,
                         const float* __restrict__ pg,
                         const float* __restrict__ pb,
                         const float* __restrict__ prm,
                         const float* __restrict__ prv,
                         float* __restrict__ out) {
    extern __shared__ __align__(16) char smem[];
    unsigned short* featU = (unsigned short*)(smem + OFF_QC);   // [208][72] overlay
    unsigned short* qc    = (unsigned short*)(smem + OFF_QC);   // [208][40] [qh|ql]
    unsigned short* Pb0   = (unsigned short*)(smem + OFF_P0);
    unsigned short* Pb1   = (unsigned short*)(smem + OFF_P1);
    float*          qraw  = (float*)(smem + OFF_QRAW);          // [16][208]
    unsigned short* kb1   = (unsigned short*)(smem + OFF_KB1);  // [224][40] [kh|kh]
    unsigned short* kb2   = (unsigned short*)(smem + OFF_KB2);  // [224][40] [kl|0]
    unsigned short* vbH   = (unsigned short*)(smem + OFF_VBH);  // [64][232]
    unsigned short* vbL   = (unsigned short*)(smem + OFF_VBL);
    float*          den4  = (float*)(smem + OFF_DEN4);          // [208][4]
    float*          sbT   = (float*)(smem + OFF_SB);
    float*          tbT   = (float*)(smem + OFF_TB);
    float*          dwsT  = (float*)(smem + OFF_DWS);
    float*          dwtT  = (float*)(smem + OFF_DWT);

    const int b    = blockIdx.x;
    const int tid  = threadIdx.x;
    const int w    = tid >> 6;
    const int li   = tid & 15;
    const int quad = (tid >> 4) & 3;
    const int tn0  = tid % NQ;     // walk seeds
    const int tc0  = tid / NQ;

    // ---- init: zero ALL of LDS (pads must be exactly 0 for MFMA k-padding) ----
    for (int t = tid; t < SMEM_BYTES / 4; t += 1024) ((unsigned int*)smem)[t] = 0u;
    __syncthreads();
    // feat = bf16(x chunk 0), layout [n][72c]
    for (int t = tid; t < VD * NQ; t += 1024) {
        int n = t % NQ, c = t / NQ;
        featU[n * 72 + c] = f2bf(x[((size_t)b * DIM + c) * NQ + n]);
    }
    __syncthreads();

    for (int h = 0; h < HEADS; ++h) {
        // ---- prologue: fold BN into (s,t) tables ----
        if (tid < 96) {
            float s = qkv_g[h * 96 + tid] * rsqrtf(qkv_rv[h * 96 + tid] + 1e-5f);
            sbT[tid] = s;
            tbT[tid] = qkv_b[h * 96 + tid] - qkv_rm[h * 96 + tid] * s;
        } else if (tid < 112) {
            int c = tid - 96;
            float s = dw_g[h * 16 + c] * rsqrtf(dw_rv[h * 16 + c] + 1e-5f);
            dwsT[c] = s;
            dwtT[c] = dw_b[h * 16 + c] - dw_rm[h * 16 + c] * s;
        }
        __syncthreads();

        // ---- phase B: QKV = W(hi+lo) x feat(bf16); W hi/lo PRECOMPUTED ----
        for (int T = w; T < 78; T += 16) {
            int ot = T / 13, nt = T - ot * 13;
            const size_t wb = ((size_t)h * 96 + ot * 16 + li) * 64;
            short8 ah0 = *(const short8*)(whH + wb + quad * 8);
            short8 al0 = *(const short8*)(whL + wb + quad * 8);
            short8 ah1 = *(const short8*)(whH + wb + 32 + quad * 8);
            short8 al1 = *(const short8*)(whL + wb + 32 + quad * 8);
            short8 b0 = *(const short8*)(featU + (nt * 16 + li) * 72 + quad * 8);
            short8 b1 = *(const short8*)(featU + (nt * 16 + li) * 72 + 32 + quad * 8);
            f32x4 acc = {0.f, 0.f, 0.f, 0.f};
            acc = MFMA16(ah0, b0, acc);
            acc = MFMA16(al0, b0, acc);
            acc = MFMA16(ah1, b1, acc);
            acc = MFMA16(al1, b1, acc);
            int n = nt * 16 + li;
            bool nok = (n < NQ);
            #pragma unroll
            for (int r = 0; r < 4; ++r) {
                int o = ot * 16 + quad * 4 + r;
                float val = acc[r] * sbT[o] + tbT[o];
                if (nok) {
                    if (o < 16) {
                        qraw[o * 208 + n] = val;
                    } else if (o < 32) {
                        int c = o - 16;
                        unsigned short hh = f2bf(val);
                        kb1[n * 40 + c] = hh;
                        kb1[n * 40 + 16 + c] = hh;              // duplicate kh into upper K-half
                        kb2[n * 40 + c] = f2bf(val - bf2f(hh)); // kl (upper half stays 0)
                    } else {
                        int d = o - 32;
                        unsigned short hh = f2bf(val);
                        vbH[d * 232 + n] = hh;
                        vbL[d * 232 + n] = f2bf(val - bf2f(hh));
                    }
                }
            }
        }
        __syncthreads();

        // ---- phase C: depthwise 5x5 conv + BN + *0.25 -> qc = [qh|ql] ----
        {
            int n = tn0, c = tc0, py = tn0 / 14, px = tn0 - (tn0 / 14) * 14;
            for (int t = tid; t < KD * NQ; t += 1024) {
                const float* qr = qraw + c * 208;
                const float* wdc = dw_w + ((size_t)h * KD + c) * 25;
                float accv = 0.f;
                #pragma unroll
                for (int ky = 0; ky < 5; ++ky) {
                    int yy = py + ky - 2;
                    if (yy < 0 || yy >= 14) continue;
                    #pragma unroll
                    for (int kx = 0; kx < 5; ++kx) {
                        int xx = px + kx - 2;
                        if (xx < 0 || xx >= 14) continue;
                        accv = fmaf(wdc[ky * 5 + kx], qr[yy * 14 + xx], accv);
                    }
                }
                float val = fmaf(accv, dwsT[c], dwtT[c]) * 0.25f;
                unsigned short hh = f2bf(val);
                qc[n * 40 + c] = hh;
                qc[n * 40 + 16 + c] = f2bf(val - bf2f(hh));
                n += 44; c += 5; px += 2; py += 3;
                if (px >= 14) { px -= 14; ++py; }
                if (n >= NQ) { n -= NQ; ++c; py -= 14; }
            }
        }
        if (tid < 832) den4[tid] = 0.f;
        __syncthreads();

        // ---- phase D: attention, Pb ping-pong: S(mi+1) || den(mi) || PV(mi) ----
        f32x4 pacc[4];
        #pragma unroll
        for (int s = 0; s < 4; ++s) pacc[s] = (f32x4){0.f, 0.f, 0.f, 0.f};

        auto spass = [&](int mi2, unsigned short* __restrict__ PbW) {
            for (int T = w; T < 26; T += 16) {
                int s = (T >= 13) ? 1 : 0;
                int nt = T - s * 13;
                int n0 = nt * 16;
                int mg = mi2 * 32 + s * 16 + li;       // global key index
                bool mok = (mg < NQ);
                // coalesced bias loads: for fixed (quad,r), li -> consecutive m
                float bias4[4];
                #pragma unroll
                for (int r = 0; r < 4; ++r) {
                    int n = n0 + quad * 4 + r;
                    int ni = n < NQ ? n : NQ - 1;
                    int mgi = mg < NQ ? mg : NQ - 1;
                    bias4[r] = biasg[(size_t)h * (NQ * NQ) + ni * NQ + mgi];
                }
                short8 q  = *(const short8*)(qc  + (n0 + li) * 40 + quad * 8);
                short8 k1 = *(const short8*)(kb1 + mg * 40 + quad * 8);
                short8 k2 = *(const short8*)(kb2 + mg * 40 + quad * 8);
                f32x4 acc = {0.f, 0.f, 0.f, 0.f};
                acc = MFMA16(q, k1, acc);   // qh*kh + ql*kh
                acc = MFMA16(q, k2, acc);   // qh*kl
                #pragma unroll
                for (int r = 0; r < 4; ++r) {
                    float e = mok ? __expf(acc[r] + bias4[r]) : 0.f;
                    PbW[(n0 + quad * 4 + r) * 40 + s * 16 + li] = f2bf(e);
                }
            }
        };

        spass(0, Pb0);
        __syncthreads();

        for (int mi = 0; mi < 7; ++mi) {
            unsigned short* PbR = (mi & 1) ? Pb1 : Pb0;
            unsigned short* PbW = (mi & 1) ? Pb0 : Pb1;
            if (mi < 6) spass(mi + 1, PbW);

            // den-pass: row sums of the bf16 P actually fed to MFMA
            if (tid < 832) {
                int n = tid >> 2, part = tid & 3;
                short8 pv = *(const short8*)(PbR + n * 40 + part * 8);
                float sum = 0.f;
                #pragma unroll
                for (int j = 0; j < 8; ++j) sum += bf2f((unsigned short)pv[j]);
                den4[n * 4 + part] += sum;
            }
            // PV: out += P x V(hi+lo); STATIC slot indexing (rule #20)
            #pragma unroll
            for (int slot = 0; slot < 4; ++slot) {
                int T = w + slot * 16;
                if (T < 52) {
                    int dt = T / 13, nt = T - dt * 13;
                    short8 p  = *(const short8*)(PbR + (nt * 16 + li) * 40 + quad * 8);
                    short8 vh = *(const short8*)(vbH + (dt * 16 + li) * 232 + mi * 32 + quad * 8);
                    short8 vl = *(const short8*)(vbL + (dt * 16 + li) * 232 + mi * 32 + quad * 8);
                    pacc[slot] = MFMA16(p, vh, pacc[slot]);
                    pacc[slot] = MFMA16(p, vl, pacc[slot]);
                }
            }
            __syncthreads();
        }

        // ---- PV epilogue: normalize, write new feat (bf16); static slots ----
        #pragma unroll
        for (int slot = 0; slot < 4; ++slot) {
            int T = w + slot * 16;
            if (T < 52) {
                int dt = T / 13, nt = T - dt * 13;
                int d = dt * 16 + li;
                #pragma unroll
                for (int r = 0; r < 4; ++r) {
                    int n = nt * 16 + quad * 4 + r;
                    if (n < NQ) {
                        f32x4 dv = *(const f32x4*)(den4 + n * 4);
                        float dn = (dv.x + dv.y) + (dv.z + dv.w);
                        float val = pacc[slot][r] / dn;
                        featU[n * 72 + d] = f2bf(val);
                    }
                }
            }
        }
        __syncthreads();

        // ---- yrelu write: vectorized short8, layout [b*NQ + n][256] ----
        for (int t = tid; t < (VD * NQ) / 8; t += 1024) {
            int n  = t >> 3;
            int c0 = (t & 7) * 8;
            short8 u = *(const short8*)(featU + n * 72 + c0);
            short8 ru;
            #pragma unroll
            for (int j = 0; j < 8; ++j) {
                unsigned short uu = (unsigned short)u[j];
                ru[j] = (short)((uu & 0x8000u) ? (unsigned short)0 : uu);
            }
            *(short8*)(yrelu + ((size_t)b * NQ + n) * DIM + h * VD + c0) = ru;
        }
        __syncthreads();

        // ---- cascade add for next head (direct x reads, coalesced) ----
        if (h < 3) {
            for (int t = tid; t < VD * NQ; t += 1024) {
                int n = t % NQ, c = t / NQ;
                float v = bf2f(featU[n * 72 + c]) + x[((size_t)b * DIM + (h + 1) * VD + c) * NQ + n];
                featU[n * 72 + c] = f2bf(v);
            }
            // re-zero feat pad rows 196..207 (dirtied by Pb/qc overlays)
            for (int t = tid; t < 12 * 64; t += 1024)
                featU[(NQ + t / 64) * 72 + (t & 63)] = 0;
        }
        __syncthreads();
    }

    // ================= fused projection phase (single-shot staging) =================
    // All of yrelu[b] (100 KB) staged ONCE into dead LDS as [208][264] bf16
    // (stride 264 hw -> conflict-free ds_read_b128 per 16-lane phase).
    // 7 pre-issued global loads, ONE barrier, then 208 MFMA + 104 ds_read with
    // zero barriers. acc[13] is phase-local (no cross-phase liveness -> no spill).
    {
        unsigned short* yL = (unsigned short*)smem;   // [208][264] = 109824 B
        const short8 z8 = {0, 0, 0, 0, 0, 0, 0, 0};

        // pre-issue: granule g = tid + i*1024; row = g>>5 (32 granules/row), cg = g&31
        short8 nv0, nv1, nv2, nv3, nv4, nv5, nv6;
        #define STAGE_LD(i, v) { int g = tid + (i) * 1024; int row = g >> 5, cg = g & 31; \
            v = (row < NQ) ? *(const short8*)(yrelu + ((size_t)b * NQ + row) * DIM + cg * 8) : z8; }
        STAGE_LD(0, nv0) STAGE_LD(1, nv1) STAGE_LD(2, nv2) STAGE_LD(3, nv3)
        STAGE_LD(4, nv4) STAGE_LD(5, nv5) STAGE_LD(6, nv6)
        #undef STAGE_LD
        #define STAGE_ST(i, v) { int g = tid + (i) * 1024; if (g < 208 * 32) { \
            int row = g >> 5, cg = g & 31; *(short8*)(yL + row * 264 + cg * 8) = v; } }
        STAGE_ST(0, nv0) STAGE_ST(1, nv1) STAGE_ST(2, nv2) STAGE_ST(3, nv3)
        STAGE_ST(4, nv4) STAGE_ST(5, nv5) STAGE_ST(6, nv6)
        #undef STAGE_ST
        __syncthreads();

        const int o0 = w * 16;
        const unsigned short* pHb = pwH + (size_t)(o0 + li) * 256 + quad * 8;
        const unsigned short* pLb = pwL + (size_t)(o0 + li) * 256 + quad * 8;

        f32x4 acc[13];
        #pragma unroll
        for (int nt = 0; nt < 13; ++nt) acc[nt] = (f32x4){0.f, 0.f, 0.f, 0.f};

        // same accumulation order as before (ks ascending, hi before lo) -> bit-identical
        #pragma unroll
        for (int ks = 0; ks < 8; ++ks) {
            short8 ah = *(const short8*)(pHb + ks * 32);
            short8 al = *(const short8*)(pLb + ks * 32);
            #pragma unroll
            for (int nt = 0; nt < 13; ++nt) {
                short8 bx = *(const short8*)(yL + (nt * 16 + li) * 264 + ks * 32 + quad * 8);
                acc[nt] = MFMA16(ah, bx, acc[nt]);
                acc[nt] = MFMA16(al, bx, acc[nt]);
            }
        }

        // epilogue: folded BN + fp32 store (out stays [b][o][n]; b fixed -> no div)
        #pragma unroll
        for (int r = 0; r < 4; ++r) {
            int o = o0 + quad * 4 + r;
            float s = pg[o] * rsqrtf(prv[o] + 1e-5f);
            float t = pb[o] - prm[o] * s;
            #pragma unroll
            for (int nt = 0; nt < 13; ++nt) {
                int n = nt * 16 + li;
                if (n < NQ)
                    out[(size_t)b * CHW + (size_t)o * NQ + n] = fmaf(acc[nt][r], s, t);
            }
        }
    }
}

// -------------------- launch --------------------
extern "C" void kernel_launch(void* const* d_in, const int* in_sizes, int n_in,
                              void* d_out, int out_size, void* d_ws, size_t ws_size,
                              hipStream_t stream) {
    const float* x        = (const float*)d_in[0];
    const float* qkv_w    = (const float*)d_in[1];
    const float* qkv_g    = (const float*)d_in[2];
    const float* qkv_b    = (const float*)d_in[3];
    const float* qkv_rm   = (const float*)d_in[4];
    const float* qkv_rv   = (const float*)d_in[5];
    const float* dw_w     = (const float*)d_in[6];
    const float* dw_g     = (const float*)d_in[7];
    const float* dw_b     = (const float*)d_in[8];
    const float* dw_rm    = (const float*)d_in[9];
    const float* dw_rv    = (const float*)d_in[10];
    const float* proj_w   = (const float*)d_in[11];
    const float* proj_g   = (const float*)d_in[12];
    const float* proj_b   = (const float*)d_in[13];
    const float* proj_rm  = (const float*)d_in[14];
    const float* proj_rv  = (const float*)d_in[15];
    const float* attn_bs  = (const float*)d_in[16];
    const int*   bias_idx = (const int*)d_in[17];

    char* ws = (char*)d_ws;
    float* biasg = (float*)ws;                                    // 614656 B
    unsigned short* yrelu = (unsigned short*)(ws + 614656);       // 51380224 B
    unsigned short* whH = (unsigned short*)(ws + 51994880);       // 49152 B
    unsigned short* whL = (unsigned short*)(ws + 52044032);       // 49152 B
    unsigned short* pwH = (unsigned short*)(ws + 52093184);       // 131072 B
    unsigned short* pwL = (unsigned short*)(ws + 52224256);       // 131072 B (end 52355328)

    {
        int total = HEADS * NQ * NQ + HEADS * 96 * 64 + DIM * DIM;  // 243776
        hipLaunchKernelGGL(prep_kernel, dim3((total + 255) / 256), dim3(256),
                           0, stream, attn_bs, bias_idx, qkv_w, proj_w,
                           biasg, whH, whL, pwH, pwL);
    }
    hipLaunchKernelGGL(cascade_attn_kernel, dim3(BATCH), dim3(1024),
                       SMEM_BYTES, stream,
                       x, whH, whL, qkv_g, qkv_b, qkv_rm, qkv_rv,
                       dw_w, dw_g, dw_b, dw_rm, dw_rv, biasg, yrelu,
                       pwH, pwL, proj_g, proj_b, proj_rm, proj_rv,
                       (float*)d_out);
}

// Round 9
// 502.039 us; speedup vs baseline: 1.2246x; 1.0513x over previous
//
#include <hip/hip_runtime.h>
#include <math.h>

#define BATCH 512
#define DIM 256
#define HEADS 4
#define KD 16
#define VD 64
#define NQ 196
#define CHW (DIM * NQ)   // 50176

typedef __attribute__((ext_vector_type(8))) short short8;
typedef __attribute__((ext_vector_type(4))) float f32x4;

#define MFMA16(A, B, C) __builtin_amdgcn_mfma_f32_16x16x32_bf16((A), (B), (C), 0, 0, 0)

__device__ __forceinline__ unsigned short f2bf(float f) {
    unsigned int u = __float_as_uint(f);
    u += 0x7FFFu + ((u >> 16) & 1u);          // round-to-nearest-even
    return (unsigned short)(u >> 16);
}
__device__ __forceinline__ float bf2f(unsigned short h) {
    return __uint_as_float(((unsigned int)h) << 16);
}

// ---------------- LDS layout (bytes) ----------------
// featU bf16 [208][72] = 29952 overlays QC (16640) + P0[0..13311]
#define OFF_QC    0          // bf16 [208][40] = 16640  (packed [qh|ql])
#define OFF_P0    16640      // bf16 [208][40] = 16640  (P ping)
#define OFF_P1    33280      // bf16 [208][40] = 16640  (P pong)
#define OFF_QRAW  49920      // fp32 [196][17] = 13328 -> pad 13344 (bank-stride 17, gcd1)
#define OFF_KB1   63264      // bf16 [224][40] = 17920  ([kh|kh])
#define OFF_KB2   81184      // bf16 [224][40] = 17920  ([kl|0])
#define OFF_VBH   99104      // bf16 [64][232] = 29696
#define OFF_VBL   128800     // bf16 [64][232] = 29696
#define OFF_DEN4  158496     // fp32 [208][4]  = 3328
#define OFF_SB    161824     // fp32 [96]
#define OFF_TB    162208     // fp32 [96]
#define OFF_DWS   162592     // fp32 [16]
#define OFF_DWT   162656     // fp32 [16]
#define SMEM_BYTES 162720    // <= 163840
// proj phase: yL bf16 [208][296] = 123136 B overlays offsets 0.. (all dead);
// stride 296 hw = 592 B -> bank stride 20 (the proven 2-way/free pattern)

// -------------------- kernel 0: bias expand + weight hi/lo precompute ------------
__global__ __launch_bounds__(256)
void prep_kernel(const float* __restrict__ attn_biases,
                 const int* __restrict__ bias_idxs,
                 const float* __restrict__ qkv_w,
                 const float* __restrict__ proj_w,
                 float* __restrict__ biasg,
                 unsigned short* __restrict__ whH,
                 unsigned short* __restrict__ whL,
                 unsigned short* __restrict__ pwH,
                 unsigned short* __restrict__ pwL) {
    int i = blockIdx.x * 256 + threadIdx.x;
    const int T1 = HEADS * NQ * NQ;        // 153664
    const int T2 = HEADS * 96 * 64;        // 24576
    const int T3 = DIM * DIM;              // 65536
    if (i < T1) {
        int h = i / (NQ * NQ);
        int r = i - h * (NQ * NQ);
        biasg[i] = attn_biases[h * NQ + bias_idxs[r]];
    } else if (i < T1 + T2) {
        int j = i - T1;
        float v = qkv_w[j];
        unsigned short hh = f2bf(v);
        whH[j] = hh;
        whL[j] = f2bf(v - bf2f(hh));
    } else if (i < T1 + T2 + T3) {
        int j = i - T1 - T2;
        float v = proj_w[j];
        unsigned short hh = f2bf(v);
        pwH[j] = hh;
        pwL[j] = f2bf(v - bf2f(hh));
    }
}

// ------------- kernel 1: fused cascaded attention + projection, MFMA -------------
__global__ __launch_bounds__(1024, 4)
void cascade_attn_kernel(const float* __restrict__ x,
                         const unsigned short* __restrict__ whH,
                         const unsigned short* __restrict__ whL,
                         const float* __restrict__ qkv_g,
                         const float* __restrict__ qkv_b,
                         const float* __restrict__ qkv_rm,
                         const float* __restrict__ qkv_rv,
                         const float* __restrict__ dw_w,
                         const float* __restrict__ dw_g,
                         const float* __restrict__ dw_b,
                         const float* __restrict__ dw_rm,
                         const float* __restrict__ dw_rv,
                         const float* __restrict__ biasg,
                         unsigned short* __restrict__ yrelu,
                         const unsigned short* __restrict__ pwH,
                         const unsigned short* __restrict__ pwL,
                         const float* __restrict__ pg,
                         const float* __restrict__ pb,
                         const float* __restrict__ prm,
                         const float* __restrict__ prv,
                         float* __restrict__ out) {
    extern __shared__ __align__(16) char smem[];
    unsigned short* featU = (unsigned short*)(smem + OFF_QC);   // [208][72] overlay
    unsigned short* qc    = (unsigned short*)(smem + OFF_QC);   // [208][40] [qh|ql]
    unsigned short* Pb0   = (unsigned short*)(smem + OFF_P0);
    unsigned short* Pb1   = (unsigned short*)(smem + OFF_P1);
    float*          qraw  = (float*)(smem + OFF_QRAW);          // [196][17] (n-major)
    unsigned short* kb1   = (unsigned short*)(smem + OFF_KB1);  // [224][40] [kh|kh]
    unsigned short* kb2   = (unsigned short*)(smem + OFF_KB2);  // [224][40] [kl|0]
    unsigned short* vbH   = (unsigned short*)(smem + OFF_VBH);  // [64][232]
    unsigned short* vbL   = (unsigned short*)(smem + OFF_VBL);
    float*          den4  = (float*)(smem + OFF_DEN4);          // [208][4]
    float*          sbT   = (float*)(smem + OFF_SB);
    float*          tbT   = (float*)(smem + OFF_TB);
    float*          dwsT  = (float*)(smem + OFF_DWS);
    float*          dwtT  = (float*)(smem + OFF_DWT);

    const int b    = blockIdx.x;
    const int tid  = threadIdx.x;
    const int w    = tid >> 6;
    const int li   = tid & 15;
    const int quad = (tid >> 4) & 3;
    const int tn0  = tid % NQ;     // walk seeds (one div/mod per thread total)
    const int tc0  = tid / NQ;

    // ---- init: zero ALL of LDS (pads must be exactly 0 for MFMA k-padding) ----
    {
        uint4 z4 = {0u, 0u, 0u, 0u};
        for (int t = tid; t < SMEM_BYTES / 16; t += 1024) ((uint4*)smem)[t] = z4;
    }
    __syncthreads();
    // feat = bf16(x chunk 0), layout [n][72c]; incremental walk (1024 = 5*196 + 44)
    {
        int n = tn0, c = tc0;
        for (int t = tid; t < VD * NQ; t += 1024) {
            featU[n * 72 + c] = f2bf(x[((size_t)b * DIM + c) * NQ + n]);
            n += 44; c += 5; if (n >= NQ) { n -= NQ; ++c; }
        }
    }
    __syncthreads();

    for (int h = 0; h < HEADS; ++h) {
        // ---- prologue: fold BN into (s,t) tables ----
        if (tid < 96) {
            float s = qkv_g[h * 96 + tid] * rsqrtf(qkv_rv[h * 96 + tid] + 1e-5f);
            sbT[tid] = s;
            tbT[tid] = qkv_b[h * 96 + tid] - qkv_rm[h * 96 + tid] * s;
        } else if (tid < 112) {
            int c = tid - 96;
            float s = dw_g[h * 16 + c] * rsqrtf(dw_rv[h * 16 + c] + 1e-5f);
            dwsT[c] = s;
            dwtT[c] = dw_b[h * 16 + c] - dw_rm[h * 16 + c] * s;
        }
        __syncthreads();

        // ---- phase B: QKV = W(hi+lo) x feat(bf16); W hi/lo PRECOMPUTED ----
        for (int T = w; T < 78; T += 16) {
            int ot = T / 13, nt = T - ot * 13;
            const size_t wb = ((size_t)h * 96 + ot * 16 + li) * 64;
            short8 ah0 = *(const short8*)(whH + wb + quad * 8);
            short8 al0 = *(const short8*)(whL + wb + quad * 8);
            short8 ah1 = *(const short8*)(whH + wb + 32 + quad * 8);
            short8 al1 = *(const short8*)(whL + wb + 32 + quad * 8);
            short8 b0 = *(const short8*)(featU + (nt * 16 + li) * 72 + quad * 8);
            short8 b1 = *(const short8*)(featU + (nt * 16 + li) * 72 + 32 + quad * 8);
            f32x4 acc = {0.f, 0.f, 0.f, 0.f};
            acc = MFMA16(ah0, b0, acc);
            acc = MFMA16(al0, b0, acc);
            acc = MFMA16(ah1, b1, acc);
            acc = MFMA16(al1, b1, acc);
            int n = nt * 16 + li;
            bool nok = (n < NQ);
            #pragma unroll
            for (int r = 0; r < 4; ++r) {
                int o = ot * 16 + quad * 4 + r;
                float val = acc[r] * sbT[o] + tbT[o];
                if (nok) {
                    if (o < 16) {
                        qraw[n * 17 + o] = val;                 // [n][17] layout
                    } else if (o < 32) {
                        int c = o - 16;
                        unsigned short hh = f2bf(val);
                        kb1[n * 40 + c] = hh;
                        kb1[n * 40 + 16 + c] = hh;              // duplicate kh into upper K-half
                        kb2[n * 40 + c] = f2bf(val - bf2f(hh)); // kl (upper half stays 0)
                    } else {
                        int d = o - 32;
                        unsigned short hh = f2bf(val);
                        vbH[d * 232 + n] = hh;
                        vbL[d * 232 + n] = f2bf(val - bf2f(hh));
                    }
                }
            }
        }
        __syncthreads();

        // ---- phase C: depthwise 5x5 conv + BN + *0.25 -> qc = [qh|ql] ----
        // c-fastest walk: c = tid&15 is CONSTANT per thread -> conv weights hoisted
        // to registers once/head; qc stores are 32B-contiguous (conflict-free);
        // qraw[n][17] reads conflict-free (bank stride 17, gcd 1).
        {
            const int c = tid & 15;
            float wreg[25];
            {
                const float* wdc = dw_w + ((size_t)h * KD + c) * 25;
                #pragma unroll
                for (int j = 0; j < 25; ++j) wreg[j] = wdc[j];
            }
            const float sc = dwsT[c], tc2 = dwtT[c];
            for (int t = tid; t < KD * NQ; t += 1024) {
                int n = t >> 4;
                int py = n / 14, px = n - py * 14;
                float accv = 0.f;
                #pragma unroll
                for (int ky = 0; ky < 5; ++ky) {
                    int yy = py + ky - 2;
                    if (yy < 0 || yy >= 14) continue;
                    #pragma unroll
                    for (int kx = 0; kx < 5; ++kx) {
                        int xx = px + kx - 2;
                        if (xx < 0 || xx >= 14) continue;
                        accv = fmaf(wreg[ky * 5 + kx], qraw[(yy * 14 + xx) * 17 + c], accv);
                    }
                }
                float val = fmaf(accv, sc, tc2) * 0.25f;
                unsigned short hh = f2bf(val);
                qc[n * 40 + c] = hh;
                qc[n * 40 + 16 + c] = f2bf(val - bf2f(hh));
            }
        }
        if (tid < 832) den4[tid] = 0.f;
        __syncthreads();

        // ---- phase D: attention, Pb ping-pong: S(mi+1) || den(mi) || PV(mi) ----
        f32x4 pacc[4];
        #pragma unroll
        for (int s = 0; s < 4; ++s) pacc[s] = (f32x4){0.f, 0.f, 0.f, 0.f};

        auto spass = [&](int mi2, unsigned short* __restrict__ PbW) {
            for (int T = w; T < 26; T += 16) {
                int s = (T >= 13) ? 1 : 0;
                int nt = T - s * 13;
                int n0 = nt * 16;
                int mg = mi2 * 32 + s * 16 + li;       // global key index
                bool mok = (mg < NQ);
                // coalesced bias loads: for fixed (quad,r), li -> consecutive m
                float bias4[4];
                #pragma unroll
                for (int r = 0; r < 4; ++r) {
                    int n = n0 + quad * 4 + r;
                    int ni = n < NQ ? n : NQ - 1;
                    int mgi = mg < NQ ? mg : NQ - 1;
                    bias4[r] = biasg[(size_t)h * (NQ * NQ) + ni * NQ + mgi];
                }
                short8 q  = *(const short8*)(qc  + (n0 + li) * 40 + quad * 8);
                short8 k1 = *(const short8*)(kb1 + mg * 40 + quad * 8);
                short8 k2 = *(const short8*)(kb2 + mg * 40 + quad * 8);
                f32x4 acc = {0.f, 0.f, 0.f, 0.f};
                acc = MFMA16(q, k1, acc);   // qh*kh + ql*kh
                acc = MFMA16(q, k2, acc);   // qh*kl
                #pragma unroll
                for (int r = 0; r < 4; ++r) {
                    float e = mok ? __expf(acc[r] + bias4[r]) : 0.f;
                    PbW[(n0 + quad * 4 + r) * 40 + s * 16 + li] = f2bf(e);
                }
            }
        };

        spass(0, Pb0);
        __syncthreads();

        for (int mi = 0; mi < 7; ++mi) {
            unsigned short* PbR = (mi & 1) ? Pb1 : Pb0;
            unsigned short* PbW = (mi & 1) ? Pb0 : Pb1;
            if (mi < 6) spass(mi + 1, PbW);

            // den-pass: row sums of the bf16 P actually fed to MFMA
            if (tid < 832) {
                int n = tid >> 2, part = tid & 3;
                short8 pv = *(const short8*)(PbR + n * 40 + part * 8);
                float sum = 0.f;
                #pragma unroll
                for (int j = 0; j < 8; ++j) sum += bf2f((unsigned short)pv[j]);
                den4[n * 4 + part] += sum;
            }
            // PV: out += P x V(hi+lo); STATIC slot indexing (rule #20)
            #pragma unroll
            for (int slot = 0; slot < 4; ++slot) {
                int T = w + slot * 16;
                if (T < 52) {
                    int dt = T / 13, nt = T - dt * 13;
                    short8 p  = *(const short8*)(PbR + (nt * 16 + li) * 40 + quad * 8);
                    short8 vh = *(const short8*)(vbH + (dt * 16 + li) * 232 + mi * 32 + quad * 8);
                    short8 vl = *(const short8*)(vbL + (dt * 16 + li) * 232 + mi * 32 + quad * 8);
                    pacc[slot] = MFMA16(p, vh, pacc[slot]);
                    pacc[slot] = MFMA16(p, vl, pacc[slot]);
                }
            }
            __syncthreads();
        }

        // ---- PV epilogue: normalize, write new feat (bf16); static slots ----
        #pragma unroll
        for (int slot = 0; slot < 4; ++slot) {
            int T = w + slot * 16;
            if (T < 52) {
                int dt = T / 13, nt = T - dt * 13;
                int d = dt * 16 + li;
                #pragma unroll
                for (int r = 0; r < 4; ++r) {
                    int n = nt * 16 + quad * 4 + r;
                    if (n < NQ) {
                        f32x4 dv = *(const f32x4*)(den4 + n * 4);
                        float dn = (dv.x + dv.y) + (dv.z + dv.w);
                        float val = pacc[slot][r] / dn;
                        featU[n * 72 + d] = f2bf(val);
                    }
                }
            }
        }
        __syncthreads();

        // ---- yrelu write: vectorized short8, layout [b*NQ + n][256] ----
        for (int t = tid; t < (VD * NQ) / 8; t += 1024) {
            int n  = t >> 3;
            int c0 = (t & 7) * 8;
            short8 u = *(const short8*)(featU + n * 72 + c0);
            short8 ru;
            #pragma unroll
            for (int j = 0; j < 8; ++j) {
                unsigned short uu = (unsigned short)u[j];
                ru[j] = (short)((uu & 0x8000u) ? (unsigned short)0 : uu);
            }
            *(short8*)(yrelu + ((size_t)b * NQ + n) * DIM + h * VD + c0) = ru;
        }
        __syncthreads();

        // ---- cascade add for next head (incremental walk, coalesced x reads) ----
        if (h < 3) {
            int n = tn0, c = tc0;
            for (int t = tid; t < VD * NQ; t += 1024) {
                float v = bf2f(featU[n * 72 + c]) + x[((size_t)b * DIM + (h + 1) * VD + c) * NQ + n];
                featU[n * 72 + c] = f2bf(v);
                n += 44; c += 5; if (n >= NQ) { n -= NQ; ++c; }
            }
            // re-zero feat pad rows 196..207 (dirtied by Pb/qc overlays)
            for (int t = tid; t < 12 * 64; t += 1024)
                featU[(NQ + t / 64) * 72 + (t & 63)] = 0;
        }
        __syncthreads();
    }

    // ================= fused projection phase (single-shot staging) =================
    // All of yrelu[b] (100 KB) staged ONCE into dead LDS as [208][296] bf16
    // (stride 296 hw = 592 B -> bank stride 20: the proven 2-way/free pattern).
    // 7 pre-issued global loads, ONE barrier, then 208 MFMA + 104 ds_read with
    // zero barriers. acc[13] is phase-local (no cross-phase liveness -> no spill).
    {
        unsigned short* yL = (unsigned short*)smem;   // [208][296] = 123136 B
        const short8 z8 = {0, 0, 0, 0, 0, 0, 0, 0};

        // pre-issue: granule g = tid + i*1024; row = g>>5 (32 granules/row), cg = g&31
        short8 nv0, nv1, nv2, nv3, nv4, nv5, nv6;
        #define STAGE_LD(i, v) { int g = tid + (i) * 1024; int row = g >> 5, cg = g & 31; \
            v = (row < NQ) ? *(const short8*)(yrelu + ((size_t)b * NQ + row) * DIM + cg * 8) : z8; }
        STAGE_LD(0, nv0) STAGE_LD(1, nv1) STAGE_LD(2, nv2) STAGE_LD(3, nv3)
        STAGE_LD(4, nv4) STAGE_LD(5, nv5) STAGE_LD(6, nv6)
        #undef STAGE_LD
        #define STAGE_ST(i, v) { int g = tid + (i) * 1024; if (g < 208 * 32) { \
            int row = g >> 5, cg = g & 31; *(short8*)(yL + row * 296 + cg * 8) = v; } }
        STAGE_ST(0, nv0) STAGE_ST(1, nv1) STAGE_ST(2, nv2) STAGE_ST(3, nv3)
        STAGE_ST(4, nv4) STAGE_ST(5, nv5) STAGE_ST(6, nv6)
        #undef STAGE_ST
        __syncthreads();

        const int o0 = w * 16;
        const unsigned short* pHb = pwH + (size_t)(o0 + li) * 256 + quad * 8;
        const unsigned short* pLb = pwL + (size_t)(o0 + li) * 256 + quad * 8;

        f32x4 acc[13];
        #pragma unroll
        for (int nt = 0; nt < 13; ++nt) acc[nt] = (f32x4){0.f, 0.f, 0.f, 0.f};

        // same accumulation order as before (ks ascending, hi before lo) -> bit-identical
        #pragma unroll
        for (int ks = 0; ks < 8; ++ks) {
            short8 ah = *(const short8*)(pHb + ks * 32);
            short8 al = *(const short8*)(pLb + ks * 32);
            #pragma unroll
            for (int nt = 0; nt < 13; ++nt) {
                short8 bx = *(const short8*)(yL + (nt * 16 + li) * 296 + ks * 32 + quad * 8);
                acc[nt] = MFMA16(ah, bx, acc[nt]);
                acc[nt] = MFMA16(al, bx, acc[nt]);
            }
        }

        // epilogue: folded BN + fp32 store (out stays [b][o][n]; b fixed -> no div)
        #pragma unroll
        for (int r = 0; r < 4; ++r) {
            int o = o0 + quad * 4 + r;
            float s = pg[o] * rsqrtf(prv[o] + 1e-5f);
            float t = pb[o] - prm[o] * s;
            #pragma unroll
            for (int nt = 0; nt < 13; ++nt) {
                int n = nt * 16 + li;
                if (n < NQ)
                    out[(size_t)b * CHW + (size_t)o * NQ + n] = fmaf(acc[nt][r], s, t);
            }
        }
    }
}

// -------------------- launch --------------------
extern "C" void kernel_launch(void* const* d_in, const int* in_sizes, int n_in,
                              void* d_out, int out_size, void* d_ws, size_t ws_size,
                              hipStream_t stream) {
    const float* x        = (const float*)d_in[0];
    const float* qkv_w    = (const float*)d_in[1];
    const float* qkv_g    = (const float*)d_in[2];
    const float* qkv_b    = (const float*)d_in[3];
    const float* qkv_rm   = (const float*)d_in[4];
    const float* qkv_rv   = (const float*)d_in[5];
    const float* dw_w     = (const float*)d_in[6];
    const float* dw_g     = (const float*)d_in[7];
    const float* dw_b     = (const float*)d_in[8];
    const float* dw_rm    = (const float*)d_in[9];
    const float* dw_rv    = (const float*)d_in[10];
    const float* proj_w   = (const float*)d_in[11];
    const float* proj_g   = (const float*)d_in[12];
    const float* proj_b   = (const float*)d_in[13];
    const float* proj_rm  = (const float*)d_in[14];
    const float* proj_rv  = (const float*)d_in[15];
    const float* attn_bs  = (const float*)d_in[16];
    const int*   bias_idx = (const int*)d_in[17];

    char* ws = (char*)d_ws;
    float* biasg = (float*)ws;                                    // 614656 B
    unsigned short* yrelu = (unsigned short*)(ws + 614656);       // 51380224 B
    unsigned short* whH = (unsigned short*)(ws + 51994880);       // 49152 B
    unsigned short* whL = (unsigned short*)(ws + 52044032);       // 49152 B
    unsigned short* pwH = (unsigned short*)(ws + 52093184);       // 131072 B
    unsigned short* pwL = (unsigned short*)(ws + 52224256);       // 131072 B (end 52355328)

    {
        int total = HEADS * NQ * NQ + HEADS * 96 * 64 + DIM * DIM;  // 243776
        hipLaunchKernelGGL(prep_kernel, dim3((total + 255) / 256), dim3(256),
                           0, stream, attn_bs, bias_idx, qkv_w, proj_w,
                           biasg, whH, whL, pwH, pwL);
    }
    hipLaunchKernelGGL(cascade_attn_kernel, dim3(BATCH), dim3(1024),
                       SMEM_BYTES, stream,
                       x, whH, whL, qkv_g, qkv_b, qkv_rm, qkv_rv,
                       dw_w, dw_g, dw_b, dw_rm, dw_rv, biasg, yrelu,
                       pwH, pwL, proj_g, proj_b, proj_rm, proj_rv,
                       (float*)d_out);
}